// Round 9
// baseline (122.273 us; speedup 1.0000x reference)
//
#include <hip/hip_runtime.h>

#define B1 256
#define IT1 4                 // pairs per thread, kernel 1
#define CH1 (B1 * IT1)        // 1024 — MUST equal CH3 (shared block-offset tiling)
#define B3 256
#define IT3 4                 // pairs per thread, kernel 3 (16KB LDS -> 8 blocks/CU)
#define CH3 (B3 * IT3)        // 1024
#define B2 1024
#define VMAX 2.2f

typedef float f32x4 __attribute__((ext_vector_type(4)));

struct DSum { double x, y; };

__device__ __forceinline__ float fast_tanh(float x) {
  // tanh(x) = 1 - 2/(exp(2x)+1); exact at +/-inf, ~1e-6 abs error.
  float e = __expf(2.0f * x);
  return 1.0f - 2.0f / (e + 1.0f);
}

// atan2 via minimax atan poly on [0,1] + quadrant fixup. ~1e-4 rad abs error.
__device__ __forceinline__ float fast_atan2(float y, float x) {
  float ax = fabsf(x), ay = fabsf(y);
  float mn = fminf(ax, ay), mx = fmaxf(ax, ay);
  float a = mn / (mx + 1e-30f);
  float s = a * a;
  float r = ((-0.0464964749f * s + 0.15931422f) * s - 0.327622764f) * s * a + a;
  if (ay > ax) r = 1.57079637f - r;
  if (x < 0.0f) r = 3.14159274f - r;
  return copysignf(r, y);
}

// Kernel 1: per-block partial sums of tanh(U)*vmax*dt (fp32 in-block, fp64 out).
__global__ __launch_bounds__(B1) void wi_partial(
    const float* __restrict__ U, const float* __restrict__ dtp,
    DSum* __restrict__ bsum, int N)
{
  const int t = threadIdx.x;
  const int lane = t & 63, wid = t >> 6;
  const long base = (long)blockIdx.x * CH1 + (long)t * IT1;
  float sx = 0.f, sy = 0.f;
  if (base + IT1 <= (long)N) {
    const f32x4* p = (const f32x4*)(U + 2 * base);
    #pragma unroll
    for (int i = 0; i < IT1 / 2; ++i) {
      f32x4 a = p[i];
      sx += fast_tanh(a.x) + fast_tanh(a.z);
      sy += fast_tanh(a.y) + fast_tanh(a.w);
    }
  } else {
    for (int i = 0; i < IT1; ++i) {
      long idx = base + i;
      if (idx < N) { sx += fast_tanh(U[2*idx]); sy += fast_tanh(U[2*idx+1]); }
    }
  }
  // wave butterfly reduce (fp32)
  #pragma unroll
  for (int o = 1; o < 64; o <<= 1) { sx += __shfl_xor(sx, o); sy += __shfl_xor(sy, o); }
  __shared__ double wsx[B1/64], wsy[B1/64];
  if (lane == 0) { wsx[wid] = (double)sx; wsy[wid] = (double)sy; }
  __syncthreads();
  if (t == 0) {
    const float sc = VMAX * (*dtp);
    double ax = 0.0, ay = 0.0;
    #pragma unroll
    for (int w = 0; w < B1/64; ++w) { ax += wsx[w]; ay += wsy[w]; }
    bsum[blockIdx.x].x = ax * (double)sc;
    bsum[blockIdx.x].y = ay * (double)sc;
  }
}

// Kernel 2: single-block fp64 exclusive scan, wave-shuffle based (2 barriers).
__global__ __launch_bounds__(B2) void wi_scan_blocks(DSum* bsum, int nblocks)
{
  const int t = threadIdx.x;
  const int lane = t & 63, wid = t >> 6;   // 16 waves
  const int per = (nblocks + B2 - 1) / B2;
  const int s = t * per;
  const int e = min(s + per, nblocks);
  double tx = 0.0, ty = 0.0;
  for (int i = s; i < e; ++i) { tx += bsum[i].x; ty += bsum[i].y; }
  // wave-level inclusive shuffle scan of thread totals (fp64)
  double ix = tx, iy = ty;
  #pragma unroll
  for (int o = 1; o < 64; o <<= 1) {
    double ux = __shfl_up(ix, o);
    double uy = __shfl_up(iy, o);
    if (lane >= o) { ix += ux; iy += uy; }
  }
  __shared__ double wx[B2/64], wy[B2/64];
  if (lane == 63) { wx[wid] = ix; wy[wid] = iy; }
  __syncthreads();
  double wbx = 0.0, wby = 0.0;
  #pragma unroll
  for (int w = 0; w < B2/64; ++w) {
    if (w < wid) { wbx += wx[w]; wby += wy[w]; }
  }
  // exclusive prefix for this thread's first element
  double rx = wbx + ix - tx;
  double ry = wby + iy - ty;
  for (int i = s; i < e; ++i) {
    double vx = bsum[i].x, vy = bsum[i].y;
    bsum[i].x = rx; bsum[i].y = ry;
    rx += vx; ry += vy;
  }
}

// Kernel 3: recompute uv, wave-shuffle scan, stage rows in LDS, emit with
// wave-contiguous non-temporal stores. IT3=4 -> 16.5KB LDS -> 8 blocks/CU.
__global__ __launch_bounds__(B3) void wi_emit(
    const float* __restrict__ U, const float* __restrict__ x0,
    const float* __restrict__ dtp, const DSum* __restrict__ boff,
    float* __restrict__ out, int N)
{
  __shared__ f32x4 stage[CH3];        // 1024 * 16 B = 16 KiB
  __shared__ float wsum_x[B3/64], wsum_y[B3/64];

  const int t = threadIdx.x;
  const int lane = t & 63, wid = t >> 6;
  const long base = (long)blockIdx.x * CH3 + (long)t * IT3;
  const float dt = *dtp;

  float vx[IT3], vy[IT3];
  const bool full = (base + IT3 <= (long)N);
  if (full) {
    const f32x4* p = (const f32x4*)(U + 2 * base);
    #pragma unroll
    for (int i = 0; i < IT3 / 2; ++i) {
      f32x4 a = p[i];
      vx[2*i]   = fast_tanh(a.x) * VMAX; vy[2*i]   = fast_tanh(a.y) * VMAX;
      vx[2*i+1] = fast_tanh(a.z) * VMAX; vy[2*i+1] = fast_tanh(a.w) * VMAX;
    }
  } else {
    for (int i = 0; i < IT3; ++i) {
      long idx = base + i;
      if (idx < N) { vx[i] = fast_tanh(U[2*idx]) * VMAX; vy[i] = fast_tanh(U[2*idx+1]) * VMAX; }
      else { vx[i] = 0.f; vy[i] = 0.f; }
    }
  }

  // thread-local inclusive prefix of uv*dt (fp32)
  float px[IT3], py[IT3];
  float sx = 0.f, sy = 0.f;
  #pragma unroll
  for (int i = 0; i < IT3; ++i) { sx += vx[i]*dt; px[i] = sx; sy += vy[i]*dt; py[i] = sy; }
  const float totx = sx, toty = sy;

  // wave-level inclusive scan of thread totals (fp32)
  #pragma unroll
  for (int o = 1; o < 64; o <<= 1) {
    float ux = __shfl_up(sx, o);
    float uy = __shfl_up(sy, o);
    if (lane >= o) { sx += ux; sy += uy; }
  }
  if (lane == 63) { wsum_x[wid] = sx; wsum_y[wid] = sy; }
  __syncthreads();
  float wbx = 0.f, wby = 0.f;
  #pragma unroll
  for (int w = 0; w < B3/64; ++w) {
    if (w < wid) { wbx += wsum_x[w]; wby += wsum_y[w]; }
  }
  const float exb = wbx + sx - totx;   // exclusive prefix within tile
  const float eyb = wby + sy - toty;

  const double ox = boff[blockIdx.x].x + (double)x0[0];
  const double oy = boff[blockIdx.x].y + (double)x0[1];

  // compute rows into LDS (XOR-swizzled)
  #pragma unroll
  for (int i = 0; i < IT3; ++i) {
    float posx = (float)(ox + (double)(exb + px[i]));
    float posy = (float)(oy + (double)(eyb + py[i]));
    float th = fast_atan2(vy[i], vx[i] + 1e-9f);
    float vv = fminf(sqrtf(vx[i]*vx[i] + vy[i]*vy[i] + 1e-12f), VMAX);
    f32x4 r; r.x = posx; r.y = posy; r.z = th; r.w = vv;
    const int k = t * IT3 + i;
    stage[k ^ ((k >> 3) & 7)] = r;
  }
  __syncthreads();

  // cooperative wave-contiguous non-temporal stores
  const long tile0 = (long)blockIdx.x * CH3;
  f32x4* o4 = (f32x4*)out;
  #pragma unroll
  for (int i = 0; i < IT3; ++i) {
    const int k = i * B3 + t;
    const long g = tile0 + k;
    if (g < (long)N) __builtin_nontemporal_store(stage[k ^ ((k >> 3) & 7)], o4 + 1 + g);
  }
  if (blockIdx.x == 0 && t == 0) {
    f32x4 r; r.x = x0[0]; r.y = x0[1]; r.z = x0[2]; r.w = x0[3];
    o4[0] = r;
  }
}

extern "C" void kernel_launch(void* const* d_in, const int* in_sizes, int n_in,
                              void* d_out, int out_size, void* d_ws, size_t ws_size,
                              hipStream_t stream) {
  const float* x0 = (const float*)d_in[0];
  const float* U  = (const float*)d_in[1];
  const float* dt = (const float*)d_in[2];
  float* out = (float*)d_out;
  const int N = in_sizes[1] / 2;
  const int nb1 = (N + CH1 - 1) / CH1;   // 16384
  const int nb3 = (N + CH3 - 1) / CH3;   // 16384 (CH1 == CH3)
  DSum* bsum = (DSum*)d_ws;              // nb1 * 16 B = 256 KiB

  wi_partial<<<nb1, B1, 0, stream>>>(U, dt, bsum, N);
  wi_scan_blocks<<<1, B2, 0, stream>>>(bsum, nb1);
  wi_emit<<<nb3, B3, 0, stream>>>(U, x0, dt, bsum, out, N);
}

// Round 10
// 113.116 us; speedup vs baseline: 1.0810x; 1.0810x over previous
//
#include <hip/hip_runtime.h>

#define B1 256
#define IT1 8                 // pairs per thread, kernel 1 (64B/lane)
#define CH1 (B1 * IT1)        // 2048 — MUST equal CH3 (shared block-offset tiling)
#define B3 256
#define IT3 8                 // rows per tile, kernel 3 (transpose layout)
#define CH3 (B3 * IT3)        // 2048
#define B2 1024
#define VMAX 2.2f

typedef float f32x4 __attribute__((ext_vector_type(4)));
typedef float f32x2 __attribute__((ext_vector_type(2)));

struct DSum { double x, y; };

__device__ __forceinline__ float fast_tanh(float x) {
  // tanh(x) = 1 - 2/(exp(2x)+1); exact at +/-inf, ~1e-6 abs error.
  float e = __expf(2.0f * x);
  return 1.0f - 2.0f / (e + 1.0f);
}

// atan2 via minimax atan poly on [0,1] + quadrant fixup. ~1e-4 rad abs error.
__device__ __forceinline__ float fast_atan2(float y, float x) {
  float ax = fabsf(x), ay = fabsf(y);
  float mn = fminf(ax, ay), mx = fmaxf(ax, ay);
  float a = mn / (mx + 1e-30f);
  float s = a * a;
  float r = ((-0.0464964749f * s + 0.15931422f) * s - 0.327622764f) * s * a + a;
  if (ay > ax) r = 1.57079637f - r;
  if (x < 0.0f) r = 3.14159274f - r;
  return copysignf(r, y);
}

// Kernel 1: per-block partial sums of tanh(U)*vmax*dt (fp32 in-block, fp64 out).
__global__ __launch_bounds__(B1) void wi_partial(
    const float* __restrict__ U, const float* __restrict__ dtp,
    DSum* __restrict__ bsum, int N)
{
  const int t = threadIdx.x;
  const int lane = t & 63, wid = t >> 6;
  const long base = (long)blockIdx.x * CH1 + (long)t * IT1;
  float sx = 0.f, sy = 0.f;
  if (base + IT1 <= (long)N) {
    const f32x4* p = (const f32x4*)(U + 2 * base);
    #pragma unroll
    for (int i = 0; i < IT1 / 2; ++i) {
      f32x4 a = p[i];
      sx += fast_tanh(a.x) + fast_tanh(a.z);
      sy += fast_tanh(a.y) + fast_tanh(a.w);
    }
  } else {
    for (int i = 0; i < IT1; ++i) {
      long idx = base + i;
      if (idx < N) { sx += fast_tanh(U[2*idx]); sy += fast_tanh(U[2*idx+1]); }
    }
  }
  // wave butterfly reduce (fp32)
  #pragma unroll
  for (int o = 1; o < 64; o <<= 1) { sx += __shfl_xor(sx, o); sy += __shfl_xor(sy, o); }
  __shared__ double wsx[B1/64], wsy[B1/64];
  if (lane == 0) { wsx[wid] = (double)sx; wsy[wid] = (double)sy; }
  __syncthreads();
  if (t == 0) {
    const float sc = VMAX * (*dtp);
    double ax = 0.0, ay = 0.0;
    #pragma unroll
    for (int w = 0; w < B1/64; ++w) { ax += wsx[w]; ay += wsy[w]; }
    bsum[blockIdx.x].x = ax * (double)sc;
    bsum[blockIdx.x].y = ay * (double)sc;
  }
}

// Kernel 2: single-block fp64 exclusive scan, wave-shuffle based (2 barriers).
__global__ __launch_bounds__(B2) void wi_scan_blocks(DSum* bsum, int nblocks)
{
  const int t = threadIdx.x;
  const int lane = t & 63, wid = t >> 6;   // 16 waves
  const int per = (nblocks + B2 - 1) / B2;
  const int s = t * per;
  const int e = min(s + per, nblocks);
  double tx = 0.0, ty = 0.0;
  for (int i = s; i < e; ++i) { tx += bsum[i].x; ty += bsum[i].y; }
  // wave-level inclusive shuffle scan of thread totals (fp64)
  double ix = tx, iy = ty;
  #pragma unroll
  for (int o = 1; o < 64; o <<= 1) {
    double ux = __shfl_up(ix, o);
    double uy = __shfl_up(iy, o);
    if (lane >= o) { ix += ux; iy += uy; }
  }
  __shared__ double wx[B2/64], wy[B2/64];
  if (lane == 63) { wx[wid] = ix; wy[wid] = iy; }
  __syncthreads();
  double wbx = 0.0, wby = 0.0;
  #pragma unroll
  for (int w = 0; w < B2/64; ++w) {
    if (w < wid) { wbx += wx[w]; wby += wy[w]; }
  }
  // exclusive prefix for this thread's first element
  double rx = wbx + ix - tx;
  double ry = wby + iy - ty;
  for (int i = s; i < e; ++i) {
    double vx = bsum[i].x, vy = bsum[i].y;
    bsum[i].x = rx; bsum[i].y = ry;
    rx += vx; ry += vy;
  }
}

// Kernel 3 (transpose layout): tile = IT3 rows x B3 cols, thread t owns column t.
// Loads 8B/lane coalesced; per-row block scans via wave shuffles (1 barrier);
// stores directly wave-contiguous (16B/lane dense) -> no LDS staging phase.
__global__ __launch_bounds__(B3) void wi_emit(
    const float* __restrict__ U, const float* __restrict__ x0,
    const float* __restrict__ dtp, const DSum* __restrict__ boff,
    float* __restrict__ out, int N)
{
  const int t = threadIdx.x;
  const int lane = t & 63, wid = t >> 6;   // 4 waves
  const long tile0 = (long)blockIdx.x * CH3;
  const float dt = *dtp;

  float uvx[IT3], uvy[IT3];
  #pragma unroll
  for (int r = 0; r < IT3; ++r) {
    const long idx = tile0 + (long)r * B3 + t;
    f32x2 a;
    if (idx < (long)N) a = *(const f32x2*)(U + 2 * idx);
    else { a.x = 0.f; a.y = 0.f; }
    uvx[r] = fast_tanh(a.x) * VMAX;
    uvy[r] = fast_tanh(a.y) * VMAX;
  }

  // per-row wave-inclusive scans of uv*dt (independent chains -> good ILP)
  float isx[IT3], isy[IT3];
  #pragma unroll
  for (int r = 0; r < IT3; ++r) { isx[r] = uvx[r] * dt; isy[r] = uvy[r] * dt; }
  #pragma unroll
  for (int o = 1; o < 64; o <<= 1) {
    #pragma unroll
    for (int r = 0; r < IT3; ++r) {
      float ux = __shfl_up(isx[r], o);
      float uy = __shfl_up(isy[r], o);
      if (lane >= o) { isx[r] += ux; isy[r] += uy; }
    }
  }

  // publish per-wave totals per row, then combine cross-wave + cross-row
  __shared__ float wtx[IT3][B3/64], wty[IT3][B3/64];
  if (lane == 63) {
    #pragma unroll
    for (int r = 0; r < IT3; ++r) { wtx[r][wid] = isx[r]; wty[r][wid] = isy[r]; }
  }
  __syncthreads();
  float offx[IT3], offy[IT3];
  float rax = 0.f, ray = 0.f;   // running sum of full rows above
  #pragma unroll
  for (int r = 0; r < IT3; ++r) {
    float wox = 0.f, woy = 0.f, rtx = 0.f, rty = 0.f;
    #pragma unroll
    for (int w = 0; w < B3/64; ++w) {
      float a = wtx[r][w], b = wty[r][w];
      if (w < wid) { wox += a; woy += b; }
      rtx += a; rty += b;
    }
    offx[r] = rax + wox; offy[r] = ray + woy;
    rax += rtx; ray += rty;
  }

  const double ox = boff[blockIdx.x].x + (double)x0[0];
  const double oy = boff[blockIdx.x].y + (double)x0[1];
  f32x4* o4 = (f32x4*)out;
  #pragma unroll
  for (int r = 0; r < IT3; ++r) {
    const long idx = tile0 + (long)r * B3 + t;
    if (idx < (long)N) {
      float posx = (float)(ox + (double)(offx[r] + isx[r]));
      float posy = (float)(oy + (double)(offy[r] + isy[r]));
      float th = fast_atan2(uvy[r], uvx[r] + 1e-9f);
      float vv = fminf(sqrtf(uvx[r]*uvx[r] + uvy[r]*uvy[r] + 1e-12f), VMAX);
      f32x4 rr; rr.x = posx; rr.y = posy; rr.z = th; rr.w = vv;
      __builtin_nontemporal_store(rr, o4 + 1 + idx);
    }
  }
  if (blockIdx.x == 0 && t == 0) {
    f32x4 rr; rr.x = x0[0]; rr.y = x0[1]; rr.z = x0[2]; rr.w = x0[3];
    o4[0] = rr;
  }
}

extern "C" void kernel_launch(void* const* d_in, const int* in_sizes, int n_in,
                              void* d_out, int out_size, void* d_ws, size_t ws_size,
                              hipStream_t stream) {
  const float* x0 = (const float*)d_in[0];
  const float* U  = (const float*)d_in[1];
  const float* dt = (const float*)d_in[2];
  float* out = (float*)d_out;
  const int N = in_sizes[1] / 2;
  const int nb1 = (N + CH1 - 1) / CH1;   // 8192
  const int nb3 = (N + CH3 - 1) / CH3;   // 8192 (CH1 == CH3)
  DSum* bsum = (DSum*)d_ws;              // nb1 * 16 B = 128 KiB

  wi_partial<<<nb1, B1, 0, stream>>>(U, dt, bsum, N);
  wi_scan_blocks<<<1, B2, 0, stream>>>(bsum, nb1);
  wi_emit<<<nb3, B3, 0, stream>>>(U, x0, dt, bsum, out, N);
}